// Round 5
// baseline (211.017 us; speedup 1.0000x reference)
//
#include <hip/hip_runtime.h>
#include <hip/hip_bf16.h>

// BatchedNLM: per-neuron 2-layer GLU MLP.
//   state_trace (128,2048,32) f32, fc1_w (2048,32,256), fc1_b (2048,256),
//   fc2_w (2048,128,2), fc2_b (2048,2), T (1)  ->  out (128,2048) f32
//
// R11: WAVE-AUTONOMOUS. One wave = one neuron (grid 2048 x 64 thr).
// W1[n] (32KB) lives in 64 VGPRs as bf16 MFMA B-fragments, loaded DIRECTLY
// from global in fragment layout (lane(m,quad) reads W1[quad*8+e][16p+m]);
// the 8 batch-tiles stream against it (128 MFMAs/wave = whole GEMM1).
// No W1 LDS, no staging barriers, no inter-wave coupling -> no convoys.
// GLU1 pairs (h,h+128)=tiles(p,p+8) register-only; fc1 bias as MFMA C-init;
// fc2 folded as per-lane partials + shfl_xor tree.
//
// History:
// R4/R7 FAILED: register-staging w1 under tight cap spills (R7: 113 MB).
// R5 WIN: w1 via global_load_lds width=16. R6 (~40us): rcp-sigmoid, LDS alias.
// R8 NEUTRAL (41us): 2x occupancy, no change. R9 FAILED: (512,4) -> VGPR
//     cap 64 -> 39 MB spills. R10 NEUTRAL (45us): clean pipelined version
//     (VGPR 76, no spills) didn't beat R6. Three structures, same 41-45us,
//     same FETCH 51MB, all counters idle (VALU 27%, MFMA 3.4%, HBM 14%).
//     Lesson: barrier-lockstepped 8-wave blocks convoy on any wave's
//     latency; pipelining inside that structure doesn't help. -> R11
//     removes barriers entirely.

#define NN 2048

typedef __attribute__((ext_vector_type(8))) short short8;
typedef __attribute__((ext_vector_type(4))) float floatx4;
typedef __attribute__((ext_vector_type(4))) int int4v;

static __device__ __forceinline__ unsigned int pkbf(float a, float b) {
    __hip_bfloat162 h = __float22bfloat162_rn(make_float2(a, b));  // v_cvt_pk_bf16_f32
    return *(unsigned int*)&h;
}

static __device__ __forceinline__ float sigmoidf_(float x) {
    return __builtin_amdgcn_rcpf(1.0f + __expf(-x));  // mul+exp+add+rcp
}

static __device__ __forceinline__ short8 pack_afrag(floatx4 a0, floatx4 a1) {
    union { int4v i; short8 s; } u;
    u.i[0] = pkbf(a0[0], a0[1]);
    u.i[1] = pkbf(a0[2], a0[3]);
    u.i[2] = pkbf(a1[0], a1[1]);
    u.i[3] = pkbf(a1[2], a1[3]);
    return u.s;
}

__global__ __launch_bounds__(64, 4)   // cap 128 VGPR; liveness ~115
void nlm_kernel(const float* __restrict__ st,
                const float* __restrict__ w1,
                const float* __restrict__ b1,
                const float* __restrict__ w2,
                const float* __restrict__ b2,
                const float* __restrict__ Tp,
                float* __restrict__ out_t)
{
    const int n    = blockIdx.x;
    const int lane = threadIdx.x;    // 0..63 (one wave)
    const int m    = lane & 15;      // A row / C col
    const int quad = lane >> 4;      // k-quad / C row group

    __shared__ float4 ldsP[128];     // {b1[h], b1[128+h], w2[2h], w2[2h+1]}
    __shared__ float  ldsO[128];     // output row staging

    // ---- params: 64 lanes x 2 entries ----
    {
        const float* b1p = b1 + (size_t)n * 256;
        const float* w2p = w2 + (size_t)n * 256;
        #pragma unroll
        for (int j = 0; j < 2; ++j) {
            const int hh = lane + 64 * j;
            ldsP[hh] = make_float4(b1p[hh], b1p[128 + hh],
                                   w2p[2 * hh], w2p[2 * hh + 1]);
        }
    }
    const float bb0  = b2[n * 2 + 0];
    const float bb1  = b2[n * 2 + 1];
    const float invT = 1.0f / Tp[0];

    // ---- W1 -> 16 bf16 B-fragments (64 VGPR), straight from global ----
    // Fragment layout (matches verified ldsB path): lane(m,quad), tile p,
    // short e  <->  W1[k = quad*8 + e][h = 16p + m], pairs packed along e.
    // Per load instr: lanes m=0..15 consecutive h -> 64B segments x 4 quads.
    short8 wf[16];
    {
        const float* gW = w1 + (size_t)n * 8192 + (size_t)(quad * 8) * 256 + m;
        #pragma unroll
        for (int p = 0; p < 16; ++p) {
            float v[8];
            #pragma unroll
            for (int e = 0; e < 8; ++e)
                v[e] = gW[e * 256 + p * 16];
            union { int4v i; short8 s; } u;
            u.i[0] = pkbf(v[0], v[1]);
            u.i[1] = pkbf(v[2], v[3]);
            u.i[2] = pkbf(v[4], v[5]);
            u.i[3] = pkbf(v[6], v[7]);
            wf[p] = u.s;
        }
    }

    __syncthreads();   // ldsP visible (1-wave block: ~free)

    // ---- stream 8 batch-tiles against register-resident W1 ----
    // unroll 2: allows one-ahead st prefetch, bounds load hoisting (R7 lesson).
    #pragma unroll 2
    for (int mt = 0; mt < 8; ++mt) {
        const int b = mt * 16 + m;
        const float* sp = st + (size_t)b * (NN * 32) + (size_t)n * 32 + quad * 8;
        floatx4 a0 = *(const floatx4*)sp;
        floatx4 a1 = *(const floatx4*)(sp + 4);
        short8 afrag = pack_afrag(a0, a1);

        float pacc[4][2];
        #pragma unroll
        for (int r = 0; r < 4; ++r)
            pacc[r][0] = pacc[r][1] = 0.0f;

        #pragma unroll
        for (int p = 0; p < 8; ++p) {
            float4 prm = ldsP[p * 16 + m];   // {bias_a, bias_b, w2a, w2b}, h=16p+m
            floatx4 ca = {prm.x, prm.x, prm.x, prm.x};
            floatx4 cb = {prm.y, prm.y, prm.y, prm.y};
            floatx4 xa = __builtin_amdgcn_mfma_f32_16x16x32_bf16(afrag, wf[p],     ca, 0, 0, 0);
            floatx4 xb = __builtin_amdgcn_mfma_f32_16x16x32_bf16(afrag, wf[p + 8], cb, 0, 0, 0);
            #pragma unroll
            for (int r = 0; r < 4; ++r) {
                float glu = xa[r] * sigmoidf_(xb[r]);
                pacc[r][0] += glu * prm.z;
                pacc[r][1] += glu * prm.w;
            }
        }

        // reduce fc2 partials across the 16 lanes of each quad
        #pragma unroll
        for (int r = 0; r < 4; ++r) {
            float s0 = pacc[r][0];
            float s1 = pacc[r][1];
            s0 += __shfl_xor(s0, 1);  s1 += __shfl_xor(s1, 1);
            s0 += __shfl_xor(s0, 2);  s1 += __shfl_xor(s1, 2);
            s0 += __shfl_xor(s0, 4);  s1 += __shfl_xor(s1, 4);
            s0 += __shfl_xor(s0, 8);  s1 += __shfl_xor(s1, 8);
            if (m == 0) {
                const int b_out = mt * 16 + quad * 4 + r;
                float x0 = s0 + bb0;
                float x1 = s1 + bb1;
                ldsO[b_out] = x0 * sigmoidf_(x1) * invT;
            }
        }
    }

    __syncthreads();   // ldsO visible

    // coalesced 512B row into out_t (2048,128)
    out_t[(size_t)n * 128 + lane]      = ldsO[lane];
    out_t[(size_t)n * 128 + 64 + lane] = ldsO[64 + lane];
}

// Transpose out_t (2048,128) -> out (128,2048). 32x32 tiles, 256 blocks.
__global__ __launch_bounds__(256)
void transpose_kernel(const float* __restrict__ out_t, float* __restrict__ out)
{
    __shared__ float tile[32][33];
    const int t    = threadIdx.x;
    const int bidx = blockIdx.x;           // 0..255
    const int n0   = (bidx & 63) * 32;     // 64 n-tiles
    const int b0   = (bidx >> 6) * 32;     // 4 b-tiles

    const int tx = t & 31;
    const int ty = t >> 5;                 // 0..7

    #pragma unroll
    for (int i = 0; i < 4; ++i) {
        const int nl = ty + i * 8;
        tile[nl][tx] = out_t[(size_t)(n0 + nl) * 128 + b0 + tx];
    }

    __syncthreads();

    #pragma unroll
    for (int i = 0; i < 4; ++i) {
        const int bl = ty + i * 8;
        out[(size_t)(b0 + bl) * NN + n0 + tx] = tile[tx][bl];
    }
}

extern "C" void kernel_launch(void* const* d_in, const int* in_sizes, int n_in,
                              void* d_out, int out_size, void* d_ws, size_t ws_size,
                              hipStream_t stream) {
    const float* st = (const float*)d_in[0];
    const float* w1 = (const float*)d_in[1];
    const float* b1 = (const float*)d_in[2];
    const float* w2 = (const float*)d_in[3];
    const float* b2 = (const float*)d_in[4];
    const float* T  = (const float*)d_in[5];
    float* out   = (float*)d_out;
    float* out_t = (float*)d_ws;    // 2048*128*4 = 1 MB scratch

    nlm_kernel<<<dim3(NN), dim3(64), 0, stream>>>(st, w1, b1, w2, b2, T, out_t);
    transpose_kernel<<<dim3(256), dim3(256), 0, stream>>>(out_t, out);
}

// Round 6
// 154.888 us; speedup vs baseline: 1.3624x; 1.3624x over previous
//
#include <hip/hip_runtime.h>
#include <hip/hip_bf16.h>

// BatchedNLM: per-neuron 2-layer GLU MLP.
//   state_trace (128,2048,32) f32, fc1_w (2048,32,256), fc1_b (2048,256),
//   fc2_w (2048,128,2), fc2_b (2048,2), T (1)  ->  out (128,2048) f32
//
// R12: THREE-KERNEL SPLIT to remove the scattered cold st gather from the
// lockstep region (theory: the 41us invariant of R6/R8/R10 is block-convoy
// on slowest-of-32 scattered st lines).
//   k1 st_transpose: pure streaming, reads st coalesced (32KB contig/block),
//      writes st_t = bf16 MFMA-A-fragment-major per neuron (16.8 MB in ws).
//   nlm: R8 structure, but afrag = ONE dense dwordx4 load from st_t
//      (layout-ready, zero pack work); w1 via proven global_load_lds DMA
//      + 3-barrier LDS-alias bf16 conversion.
//   transpose: unchanged (out_t -> out).
//
// History:
// R4/R7/R9/R11 FAILED: register-staging w1 spills. NOTE toolchain quirk:
//     __launch_bounds__(X, 4) caps VGPR at 64 (seen 3x); (X, 2) -> cap 128.
// R5 WIN: w1 via global_load_lds width=16. R6 (~40us): rcp-sigmoid, LDS alias.
// R8 NEUTRAL (41.4us): 2x occupancy, no change. R10 NEUTRAL (45us): DMA
//     pipelining across neurons, no change. Three structures, same 41-45us,
//     FETCH 51MB @ 1.2TB/s, all pipes idle -> the common factor is the
//     scattered st gather inside the barriered region. R12 removes it.

#define NN 2048

typedef __attribute__((ext_vector_type(8))) short short8;
typedef __attribute__((ext_vector_type(4))) float floatx4;
typedef __attribute__((ext_vector_type(4))) int int4v;

static __device__ __forceinline__ unsigned int pkbf(float a, float b) {
    __hip_bfloat162 h = __float22bfloat162_rn(make_float2(a, b));  // v_cvt_pk_bf16_f32
    return *(unsigned int*)&h;
}

static __device__ __forceinline__ float sigmoidf_(float x) {
    return __builtin_amdgcn_rcpf(1.0f + __expf(-x));  // mul+exp+add+rcp
}

static __device__ __forceinline__ void gload_lds16(const float* g, float* l) {
    // Per-lane gptr; LDS dest = wave-uniform base + lane*16B (m97/m104 semantics).
    __builtin_amdgcn_global_load_lds((const __attribute__((address_space(1))) void*)g,
                                     (__attribute__((address_space(3))) void*)l,
                                     16, 0, 0);
}

// ---------------------------------------------------------------------------
// k1: st (128,2048,32) f32  ->  st_t bf16, fragment-major per neuron.
// st_t short index: ((n*8 + mt)*64 + quad*16 + m) * 8 + e
//   holds st[b = mt*16 + m][n][k = quad*8 + e] as bf16.
// Block g: b = g&127 (fixed), n = (g>>7)*256 + t. Reads 128B contiguous per
// thread (block = 32KB contiguous); writes 4x16B (sectored, fire-and-forget).
// Pure streaming, no barriers, no dependent consumption -> latency-immune.
// ---------------------------------------------------------------------------
__global__ __launch_bounds__(256)
void st_transpose_kernel(const float* __restrict__ st, short* __restrict__ st_t)
{
    const int g = blockIdx.x;          // 0..1023
    const int t = threadIdx.x;         // 0..255
    const int b  = g & 127;
    const int n  = (g >> 7) * 256 + t;
    const int mt = b >> 4;
    const int m  = b & 15;

    const float* src = st + (size_t)b * (NN * 32) + (size_t)n * 32;
    short* dst = st_t + (size_t)n * 4096 + mt * 512 + m * 8;

    #pragma unroll
    for (int q = 0; q < 4; ++q) {
        floatx4 a0 = *(const floatx4*)(src + q * 8);
        floatx4 a1 = *(const floatx4*)(src + q * 8 + 4);
        union { int4v i; short8 s; } u;
        u.i[0] = pkbf(a0[0], a0[1]);
        u.i[1] = pkbf(a0[2], a0[3]);
        u.i[2] = pkbf(a1[0], a1[1]);
        u.i[3] = pkbf(a1[2], a1[3]);
        *(short8*)(dst + q * 128) = u.s;    // (quad*16+m)*8 = q*128 + m*8
    }
}

// ---------------------------------------------------------------------------
// nlm: one block per neuron, 512 thr = 8 waves, wave wv owns batch tile mt=wv.
// ---------------------------------------------------------------------------
__global__ __launch_bounds__(512, 2)
void nlm_kernel(const short* __restrict__ st_t,
                const float* __restrict__ w1,
                const float* __restrict__ b1,
                const float* __restrict__ w2,
                const float* __restrict__ b2,
                const float* __restrict__ Tp,
                float* __restrict__ out_t)
{
    const int n = blockIdx.x;
    const int t = threadIdx.x;     // 0..511

    // ldsW: raw f32 W1[n] (32 KB); first 16 KB reused as bf16 buffer after
    // the conv-read barrier (R6-proven aliasing).
    __shared__ __align__(16) float  ldsW[32 * 256];
    __shared__ float4 ldsP[128];          // {b1[h], b1[128+h], w2[2h], w2[2h+1]}
    __shared__ float  ldsO[128];
    short* ldsB = (short*)ldsW;

    const int lane = t & 63;
    const int wv   = t >> 6;      // wave 0..7 = batch tile mt
    const int m    = lane & 15;   // A row / C col
    const int quad = lane >> 4;   // k-quad / C row group

    // ---- 1) Async DMA: W1[n] (32 KB f32) -> ldsW. 4 instrs/wave. ----
    {
        const float* gW = w1 + (size_t)n * 8192;
        #pragma unroll
        for (int i = 0; i < 4; ++i) {
            const int off = wv * 1024 + i * 256;      // floats, wave-uniform
            gload_lds16(gW + off + lane * 4, &ldsW[off]);
        }
    }

    // ---- 2) afrag: ONE dense coalesced 16B load, layout-ready bf16 ----
    short8 afrag = *(const short8*)(st_t + (size_t)n * 4096 + wv * 512 + lane * 8);

    if (t < 128) {
        const float* b1p = b1 + (size_t)n * 256;
        const float* w2p = w2 + (size_t)n * 256;
        float  pba = b1p[t];
        float  pbb = b1p[128 + t];
        float2 pw2 = *(const float2*)(w2p + 2 * t);
        ldsP[t] = make_float4(pba, pbb, pw2.x, pw2.y);
    }

    const float bb0  = b2[n * 2 + 0];
    const float bb1  = b2[n * 2 + 1];
    const float invT = 1.0f / Tp[0];

    __syncthreads();   // drains DMA (vmcnt) + LDS writes

    // ---- 3) In-place conversion: ldsW f32 -> regs -> ldsB bf16 ----
    float w[16];
    const int h  = t & 255;
    const int kh = t >> 8;
    #pragma unroll
    for (int k = 0; k < 16; ++k)
        w[k] = ldsW[(kh * 16 + k) * 256 + h];

    __syncthreads();   // all f32 reads done before bf16 overwrite

    {
        // fragment-major short idx = (h>>4)*512 + (k>>3)*128 + (h&15)*8 + (k&7)
        const int base = ((h >> 4) * 512) + ((h & 15) * 8) + kh * 256;
        #pragma unroll
        for (int q = 0; q < 2; ++q) {
            union { int4v iv; short8 s; } u;
            #pragma unroll
            for (int e = 0; e < 4; ++e)
                u.iv[e] = pkbf(w[q * 8 + 2 * e], w[q * 8 + 2 * e + 1]);
            *(short8*)&ldsB[base + q * 128] = u.s;
        }
    }

    __syncthreads();

    // ---- 4) Compute: 8 tile-pairs, fc1 bias as MFMA C-init, fc2 folded ----
    float pacc[4][2];
    #pragma unroll
    for (int r = 0; r < 4; ++r)
        pacc[r][0] = pacc[r][1] = 0.0f;

    #pragma unroll
    for (int p = 0; p < 8; ++p) {
        short8 bfA = *(short8*)&ldsB[(p * 64 + lane) * 8];
        short8 bfB = *(short8*)&ldsB[((p + 8) * 64 + lane) * 8];
        float4 prm = ldsP[p * 16 + m];   // {bias_a, bias_b, w2a, w2b}, h=16p+m
        floatx4 ca = {prm.x, prm.x, prm.x, prm.x};
        floatx4 cb = {prm.y, prm.y, prm.y, prm.y};
        floatx4 xa = __builtin_amdgcn_mfma_f32_16x16x32_bf16(afrag, bfA, ca, 0, 0, 0);
        floatx4 xb = __builtin_amdgcn_mfma_f32_16x16x32_bf16(afrag, bfB, cb, 0, 0, 0);
        #pragma unroll
        for (int r = 0; r < 4; ++r) {
            float glu = xa[r] * sigmoidf_(xb[r]);
            pacc[r][0] += glu * prm.z;
            pacc[r][1] += glu * prm.w;
        }
    }

    // ---- 5) Reduce fc2 partials across the 16 lanes of each quad ----
    #pragma unroll
    for (int r = 0; r < 4; ++r) {
        float s0 = pacc[r][0];
        float s1 = pacc[r][1];
        s0 += __shfl_xor(s0, 1);  s1 += __shfl_xor(s1, 1);
        s0 += __shfl_xor(s0, 2);  s1 += __shfl_xor(s1, 2);
        s0 += __shfl_xor(s0, 4);  s1 += __shfl_xor(s1, 4);
        s0 += __shfl_xor(s0, 8);  s1 += __shfl_xor(s1, 8);
        if (m == 0) {
            const int b = wv * 16 + quad * 4 + r;
            float x0 = s0 + bb0;
            float x1 = s1 + bb1;
            ldsO[b] = x0 * sigmoidf_(x1) * invT;
        }
    }

    __syncthreads();

    // One coalesced 512B row per block into out_t (2048,128).
    if (t < 128)
        out_t[(size_t)n * 128 + t] = ldsO[t];
}

// Transpose out_t (2048,128) -> out (128,2048). 32x32 tiles, 256 blocks.
__global__ __launch_bounds__(256)
void transpose_kernel(const float* __restrict__ out_t, float* __restrict__ out)
{
    __shared__ float tile[32][33];
    const int t    = threadIdx.x;
    const int bidx = blockIdx.x;           // 0..255
    const int n0   = (bidx & 63) * 32;     // 64 n-tiles
    const int b0   = (bidx >> 6) * 32;     // 4 b-tiles

    const int tx = t & 31;
    const int ty = t >> 5;                 // 0..7

    #pragma unroll
    for (int i = 0; i < 4; ++i) {
        const int nl = ty + i * 8;
        tile[nl][tx] = out_t[(size_t)(n0 + nl) * 128 + b0 + tx];
    }

    __syncthreads();

    #pragma unroll
    for (int i = 0; i < 4; ++i) {
        const int bl = ty + i * 8;
        out[(size_t)(b0 + bl) * NN + n0 + tx] = tile[tx][bl];
    }
}

extern "C" void kernel_launch(void* const* d_in, const int* in_sizes, int n_in,
                              void* d_out, int out_size, void* d_ws, size_t ws_size,
                              hipStream_t stream) {
    const float* st = (const float*)d_in[0];
    const float* w1 = (const float*)d_in[1];
    const float* b1 = (const float*)d_in[2];
    const float* w2 = (const float*)d_in[3];
    const float* b2 = (const float*)d_in[4];
    const float* T  = (const float*)d_in[5];
    float* out   = (float*)d_out;
    float* out_t = (float*)d_ws;                         // [0, 1 MB)
    short* st_t  = (short*)((char*)d_ws + (2u << 20));   // [2 MB, 2+16.8 MB)

    st_transpose_kernel<<<dim3(1024), dim3(256), 0, stream>>>(st, st_t);
    nlm_kernel<<<dim3(NN), dim3(512), 0, stream>>>(st_t, w1, b1, w2, b2, T, out_t);
    transpose_kernel<<<dim3(256), dim3(256), 0, stream>>>(out_t, out);
}

// Round 7
// 139.682 us; speedup vs baseline: 1.5107x; 1.1089x over previous
//
#include <hip/hip_runtime.h>
#include <hip/hip_bf16.h>

// BatchedNLM: per-neuron 2-layer GLU MLP.
//   state_trace (128,2048,32) f32, fc1_w (2048,32,256), fc1_b (2048,256),
//   fc2_w (2048,128,2), fc2_b (2048,2), T (1)  ->  out (128,2048) f32
//
// R13: same 3-kernel split as R12, but k1's writes made fully coalesced.
// R12's k1 wrote 16B sectors at 8KB thread-stride (~4x write amplification);
// result was ambiguous (k1+nlm ~ 66us combined, fills hide both). R13 maps
// wave<->(n,mt), lane<->(quad,m): write = 1KB contiguous per wave-instr,
// read = 32B/lane (16x128B segments/wave) streaming over n. nlm is
// byte-identical to R12 -> total-time delta cleanly attributes to k1, and
// total vs the 131.5us R8-era baseline decides the scatter-convoy theory.
//
// History:
// R4/R7/R9/R11 FAILED: register-staging w1 spills. Toolchain quirk:
//     __launch_bounds__(X,4) caps VGPR at 64 (3x); (X,2) -> cap 128.
// R5 WIN: w1 via global_load_lds width=16. R6 (~40us): rcp-sigmoid, LDS alias.
// R8/R10 NEUTRAL (41-45us): occupancy x2, cross-neuron DMA pipelining ->
//     no change. FETCH 51MB @ 1.2TB/s, all pipes idle. Theory: block convoys
//     on slowest-of-32 scattered st lines inside the lockstep region.
// R12: split st into streaming transpose (st_t bf16 fragment-major) so nlm's
//     A-load is one dense 16B read. k1's own writes scattered -> ambiguous.

#define NN 2048

typedef __attribute__((ext_vector_type(8))) short short8;
typedef __attribute__((ext_vector_type(4))) float floatx4;
typedef __attribute__((ext_vector_type(4))) int int4v;

static __device__ __forceinline__ unsigned int pkbf(float a, float b) {
    __hip_bfloat162 h = __float22bfloat162_rn(make_float2(a, b));  // v_cvt_pk_bf16_f32
    return *(unsigned int*)&h;
}

static __device__ __forceinline__ float sigmoidf_(float x) {
    return __builtin_amdgcn_rcpf(1.0f + __expf(-x));  // mul+exp+add+rcp
}

static __device__ __forceinline__ void gload_lds16(const float* g, float* l) {
    // Per-lane gptr; LDS dest = wave-uniform base + lane*16B (m97/m104 semantics).
    __builtin_amdgcn_global_load_lds((const __attribute__((address_space(1))) void*)g,
                                     (__attribute__((address_space(3))) void*)l,
                                     16, 0, 0);
}

// ---------------------------------------------------------------------------
// k1: st (128,2048,32) f32  ->  st_t bf16, fragment-major per neuron.
// st_t short index: n*4096 + mt*512 + quad*128 + m*8 + e
//   holds st[b = mt*16 + m][n][k = quad*8 + e] as bf16.
// Wave <-> (n, mt); lane: m = lane&15, quad = lane>>4.
//   read : lane loads 32B contig at st[b][n][quad*8..+8]
//          (per wave: 16 segments x 128B, streaming over n, same 16 b-rows
//           per block -> L2-friendly)
//   write: lane stores 16B at st_t + n*4096 + mt*512 + lane*16B
//          -> 1KB fully contiguous per wave-instr.
// No LDS, no barriers, 8 independent iters/wave -> latency-immune.
// ---------------------------------------------------------------------------
__global__ __launch_bounds__(256)
void st_transpose_kernel(const float* __restrict__ st, short* __restrict__ st_t)
{
    const int t    = threadIdx.x;       // 0..255
    const int lane = t & 63;
    const int wv   = t >> 6;            // 0..3
    const int mt   = blockIdx.x & 7;    // batch tile
    const int g    = blockIdx.x >> 3;   // 0..63 n-group
    const int m    = lane & 15;
    const int quad = lane >> 4;

    const int b = mt * 16 + m;
    const float* src = st + (size_t)b * (NN * 32) + (size_t)quad * 8;
    short* dstbase = st_t + (size_t)mt * 512 + (size_t)lane * 8;

    const int n0 = g * 32 + wv;         // wave handles n = n0 + 4*i, i<8
    #pragma unroll
    for (int i = 0; i < 8; ++i) {
        const int n = n0 + i * 4;
        floatx4 a0 = *(const floatx4*)(src + (size_t)n * 32);
        floatx4 a1 = *(const floatx4*)(src + (size_t)n * 32 + 4);
        union { int4v iv; short8 s; } u;
        u.iv[0] = pkbf(a0[0], a0[1]);
        u.iv[1] = pkbf(a0[2], a0[3]);
        u.iv[2] = pkbf(a1[0], a1[1]);
        u.iv[3] = pkbf(a1[2], a1[3]);
        *(short8*)(dstbase + (size_t)n * 4096) = u.s;
    }
}

// ---------------------------------------------------------------------------
// nlm: one block per neuron, 512 thr = 8 waves, wave wv owns batch tile mt=wv.
// (byte-identical to R12)
// ---------------------------------------------------------------------------
__global__ __launch_bounds__(512, 2)
void nlm_kernel(const short* __restrict__ st_t,
                const float* __restrict__ w1,
                const float* __restrict__ b1,
                const float* __restrict__ w2,
                const float* __restrict__ b2,
                const float* __restrict__ Tp,
                float* __restrict__ out_t)
{
    const int n = blockIdx.x;
    const int t = threadIdx.x;     // 0..511

    // ldsW: raw f32 W1[n] (32 KB); first 16 KB reused as bf16 buffer after
    // the conv-read barrier (R6-proven aliasing).
    __shared__ __align__(16) float  ldsW[32 * 256];
    __shared__ float4 ldsP[128];          // {b1[h], b1[128+h], w2[2h], w2[2h+1]}
    __shared__ float  ldsO[128];
    short* ldsB = (short*)ldsW;

    const int lane = t & 63;
    const int wv   = t >> 6;      // wave 0..7 = batch tile mt
    const int m    = lane & 15;   // A row / C col
    const int quad = lane >> 4;   // k-quad / C row group

    // ---- 1) Async DMA: W1[n] (32 KB f32) -> ldsW. 4 instrs/wave. ----
    {
        const float* gW = w1 + (size_t)n * 8192;
        #pragma unroll
        for (int i = 0; i < 4; ++i) {
            const int off = wv * 1024 + i * 256;      // floats, wave-uniform
            gload_lds16(gW + off + lane * 4, &ldsW[off]);
        }
    }

    // ---- 2) afrag: ONE dense coalesced 16B load, layout-ready bf16 ----
    short8 afrag = *(const short8*)(st_t + (size_t)n * 4096 + wv * 512 + lane * 8);

    if (t < 128) {
        const float* b1p = b1 + (size_t)n * 256;
        const float* w2p = w2 + (size_t)n * 256;
        float  pba = b1p[t];
        float  pbb = b1p[128 + t];
        float2 pw2 = *(const float2*)(w2p + 2 * t);
        ldsP[t] = make_float4(pba, pbb, pw2.x, pw2.y);
    }

    const float bb0  = b2[n * 2 + 0];
    const float bb1  = b2[n * 2 + 1];
    const float invT = 1.0f / Tp[0];

    __syncthreads();   // drains DMA (vmcnt) + LDS writes

    // ---- 3) In-place conversion: ldsW f32 -> regs -> ldsB bf16 ----
    float w[16];
    const int h  = t & 255;
    const int kh = t >> 8;
    #pragma unroll
    for (int k = 0; k < 16; ++k)
        w[k] = ldsW[(kh * 16 + k) * 256 + h];

    __syncthreads();   // all f32 reads done before bf16 overwrite

    {
        // fragment-major short idx = (h>>4)*512 + (k>>3)*128 + (h&15)*8 + (k&7)
        const int base = ((h >> 4) * 512) + ((h & 15) * 8) + kh * 256;
        #pragma unroll
        for (int q = 0; q < 2; ++q) {
            union { int4v iv; short8 s; } u;
            #pragma unroll
            for (int e = 0; e < 4; ++e)
                u.iv[e] = pkbf(w[q * 8 + 2 * e], w[q * 8 + 2 * e + 1]);
            *(short8*)&ldsB[base + q * 128] = u.s;
        }
    }

    __syncthreads();

    // ---- 4) Compute: 8 tile-pairs, fc1 bias as MFMA C-init, fc2 folded ----
    float pacc[4][2];
    #pragma unroll
    for (int r = 0; r < 4; ++r)
        pacc[r][0] = pacc[r][1] = 0.0f;

    #pragma unroll
    for (int p = 0; p < 8; ++p) {
        short8 bfA = *(short8*)&ldsB[(p * 64 + lane) * 8];
        short8 bfB = *(short8*)&ldsB[((p + 8) * 64 + lane) * 8];
        float4 prm = ldsP[p * 16 + m];   // {bias_a, bias_b, w2a, w2b}, h=16p+m
        floatx4 ca = {prm.x, prm.x, prm.x, prm.x};
        floatx4 cb = {prm.y, prm.y, prm.y, prm.y};
        floatx4 xa = __builtin_amdgcn_mfma_f32_16x16x32_bf16(afrag, bfA, ca, 0, 0, 0);
        floatx4 xb = __builtin_amdgcn_mfma_f32_16x16x32_bf16(afrag, bfB, cb, 0, 0, 0);
        #pragma unroll
        for (int r = 0; r < 4; ++r) {
            float glu = xa[r] * sigmoidf_(xb[r]);
            pacc[r][0] += glu * prm.z;
            pacc[r][1] += glu * prm.w;
        }
    }

    // ---- 5) Reduce fc2 partials across the 16 lanes of each quad ----
    #pragma unroll
    for (int r = 0; r < 4; ++r) {
        float s0 = pacc[r][0];
        float s1 = pacc[r][1];
        s0 += __shfl_xor(s0, 1);  s1 += __shfl_xor(s1, 1);
        s0 += __shfl_xor(s0, 2);  s1 += __shfl_xor(s1, 2);
        s0 += __shfl_xor(s0, 4);  s1 += __shfl_xor(s1, 4);
        s0 += __shfl_xor(s0, 8);  s1 += __shfl_xor(s1, 8);
        if (m == 0) {
            const int b = wv * 16 + quad * 4 + r;
            float x0 = s0 + bb0;
            float x1 = s1 + bb1;
            ldsO[b] = x0 * sigmoidf_(x1) * invT;
        }
    }

    __syncthreads();

    // One coalesced 512B row per block into out_t (2048,128).
    if (t < 128)
        out_t[(size_t)n * 128 + t] = ldsO[t];
}

// Transpose out_t (2048,128) -> out (128,2048). 32x32 tiles, 256 blocks.
__global__ __launch_bounds__(256)
void transpose_kernel(const float* __restrict__ out_t, float* __restrict__ out)
{
    __shared__ float tile[32][33];
    const int t    = threadIdx.x;
    const int bidx = blockIdx.x;           // 0..255
    const int n0   = (bidx & 63) * 32;     // 64 n-tiles
    const int b0   = (bidx >> 6) * 32;     // 4 b-tiles

    const int tx = t & 31;
    const int ty = t >> 5;                 // 0..7

    #pragma unroll
    for (int i = 0; i < 4; ++i) {
        const int nl = ty + i * 8;
        tile[nl][tx] = out_t[(size_t)(n0 + nl) * 128 + b0 + tx];
    }

    __syncthreads();

    #pragma unroll
    for (int i = 0; i < 4; ++i) {
        const int bl = ty + i * 8;
        out[(size_t)(b0 + bl) * NN + n0 + tx] = tile[tx][bl];
    }
}

extern "C" void kernel_launch(void* const* d_in, const int* in_sizes, int n_in,
                              void* d_out, int out_size, void* d_ws, size_t ws_size,
                              hipStream_t stream) {
    const float* st = (const float*)d_in[0];
    const float* w1 = (const float*)d_in[1];
    const float* b1 = (const float*)d_in[2];
    const float* w2 = (const float*)d_in[3];
    const float* b2 = (const float*)d_in[4];
    const float* T  = (const float*)d_in[5];
    float* out   = (float*)d_out;
    float* out_t = (float*)d_ws;                         // [0, 1 MB)
    short* st_t  = (short*)((char*)d_ws + (2u << 20));   // [2 MB, 2+16.8 MB)

    st_transpose_kernel<<<dim3(512), dim3(256), 0, stream>>>(st, st_t);
    nlm_kernel<<<dim3(NN), dim3(512), 0, stream>>>(st_t, w1, b1, w2, b2, T, out_t);
    transpose_kernel<<<dim3(256), dim3(256), 0, stream>>>(out_t, out);
}